// Round 12
// baseline (1129.465 us; speedup 1.0000x reference)
//
#include <hip/hip_runtime.h>
#include <hip/hip_bf16.h>

#define NVV 100000
#define NCC 400000
#define NEE 1600000

typedef short short8 __attribute__((ext_vector_type(8)));
typedef short short4v __attribute__((ext_vector_type(4)));
typedef float f32x4 __attribute__((ext_vector_type(4)));
typedef unsigned int u32x2 __attribute__((ext_vector_type(2)));
typedef unsigned int u32x4 __attribute__((ext_vector_type(4)));

__device__ __forceinline__ float b2f(short s) {
    unsigned int u = ((unsigned int)(unsigned short)s) << 16;
    return __builtin_bit_cast(float, u);
}
__device__ __forceinline__ short f2b(float f) {
    __hip_bfloat16 h = __float2bfloat16(f);
    return __builtin_bit_cast(short, h);
}
// packed f32->bf16 (RTNE), 2 elements per instruction
__device__ __forceinline__ unsigned int cvtpk(float a, float b) {
    unsigned int r;
    asm("v_cvt_pk_bf16_f32 %0, %1, %2" : "=v"(r) : "v"(a), "v"(b));
    return r;
}
// async 16B global load: compiler cannot sink it; result valid after counted vmcnt
__device__ __forceinline__ short8 gload16(const short* p) {
    short8 d;
    asm volatile("global_load_dwordx4 %0, %1, off" : "=v"(d) : "v"(p));
    return d;
}
#define SB0() __builtin_amdgcn_sched_barrier(0)

// ---------------- phase1: hist (XCD-partitioned, 2048 blocks) + f32->bf16 convert + weight prep ----------------
// blocks [0,2048): hist | [2048,4096): to_bf16 | [4096,4992): prep.
// hist atomics stay XCD-local (round-10 proven form); doubled hist TLP vs round 10.
__global__ __launch_bounds__(256)
void phase1(const int* __restrict__ row_v, const int* __restrict__ row_c,
            int* __restrict__ cnt_v, int* __restrict__ cnt_c,
            const float* __restrict__ hv, const float* __restrict__ hc,
            short* __restrict__ hvb, short* __restrict__ hcb,
            const float* __restrict__ mw1, const float* __restrict__ mw2,
            const float* __restrict__ uw1, const float* __restrict__ uw2,
            short* __restrict__ wt_m1, short* __restrict__ wt_m2,
            short* __restrict__ wt_u1, short* __restrict__ wt_u2)
{
    int b = blockIdx.x;
    if (b < 2048) {
        // XCD-partitioned histogram: group g owns row slice -> cnt slice stays in one L2
        const int g = b & 7;
        const int bg = b >> 3, nbg = 256;
        const int r0 = g * (NVV / 8), r1 = r0 + NVV / 8;
        for (int e = bg * 256 + threadIdx.x; e < NEE; e += nbg * 256) {
            int r = row_v[e];
            if (r >= r0 && r < r1) atomicAdd(&cnt_v[r], 1);
        }
        const int s0 = g * (NCC / 8), s1 = s0 + NCC / 8;
        for (int e = bg * 256 + threadIdx.x; e < NEE; e += nbg * 256) {
            int r = row_c[e];
            if (r >= s0 && r < s1) atomicAdd(&cnt_c[r], 1);
        }
    } else if (b < 4096) {
        const long nv = (long)NVV * 128;
        const long nc = (long)NCC * 128;
        long i0 = ((long)(b - 2048) * 256 + threadIdx.x) * 8;
        long stride = (long)2048 * 256 * 8;
        for (long i = i0; i < nv + nc; i += stride) {
            const float* in; short* outp; long j;
            if (i < nv) { in = hv; outp = hvb; j = i; }
            else        { in = hc; outp = hcb; j = i - nv; }
            f32x4 a = *(const f32x4*)(in + j);
            f32x4 bq = *(const f32x4*)(in + j + 4);
            u32x4 o;
            o[0] = cvtpk(a[0], a[1]);
            o[1] = cvtpk(a[2], a[3]);
            o[2] = cvtpk(bq[0], bq[1]);
            o[3] = cvtpk(bq[2], bq[3]);
            *(u32x4*)(outp + j) = o;
        }
    } else {
        int e = (b - 4096) * 256 + threadIdx.x;
        const float* W; short* WT; int K; int idx;
        if (e < 65536)        { W = mw1; WT = wt_m1; K = 128; idx = e; }
        else if (e < 131072)  { W = mw2; WT = wt_m2; K = 128; idx = e - 65536; }
        else if (e < 196608)  { W = uw1; WT = wt_u1; K = 256; idx = e - 131072; }
        else if (e < 229376)  { W = uw2; WT = wt_u2; K = 128; idx = e - 196608; }
        else return;
        int mk = idx >> 7, n = idx & 127;
        int mi = mk / K, k = mk - mi * K;
        WT[(size_t)mi * K * 128 + (size_t)n * K + k] = f2b(W[idx]);
    }
}

// ---------------- merged message MLP (hc sets 0,1 -> zv; hv sets 2,3 -> zc) ----------------
template<int NW>
__global__ __launch_bounds__(NW * 64, 1)
void mlp2_msg_all(const short* __restrict__ hcb, const short* __restrict__ hvb,
                  const short* __restrict__ WT1, const float* __restrict__ B1a,
                  const short* __restrict__ WT2, const float* __restrict__ B2a,
                  short* __restrict__ zv, short* __restrict__ zc, int splitC)
{
    constexpr int BM = NW * 32;
    constexpr int NT = NW * 64;
    __shared__ short sW1[128 * 136];
    __shared__ short sW2[128 * 136];
    __shared__ short sH[BM * 136];

    const int tid = threadIdx.x;
    const int lane = tid & 63;
    const int w = tid >> 6;
    const int p = lane & 15;
    const int q = lane >> 4;

    int b = blockIdx.x;
    const short* X; short* z; int M, c0, cstr, set;
    if (b < splitC) {
        set = b & 1; X = hcb; z = zv + (size_t)set * NCC * 128;
        M = NCC; c0 = b >> 1; cstr = splitC >> 1;
    } else {
        int bb = b - splitC;
        set = 2 + (bb & 1); X = hvb; z = zc + (size_t)(bb & 1) * NVV * 128;
        M = NVV; c0 = bb >> 1; cstr = (gridDim.x - splitC) >> 1;
    }
    const int nChunks = (M + BM - 1) / BM;

    const short* w1g = WT1 + set * 16384;
    const short* w2g = WT2 + set * 16384;
    const float* b1g = B1a + set * 128;
    const float* b2g = B2a + set * 128;

    for (int e = tid * 8; e < 128 * 128; e += NT * 8) {
        int n = e >> 7, k = e & 127;
        *(short8*)(sW1 + n * 136 + k) = *(const short8*)(w1g + e);
        *(short8*)(sW2 + n * 136 + k) = *(const short8*)(w2g + e);
    }
    __syncthreads();

    if (c0 >= nChunks) return;

    short8 xfA[2][4], xfB[2][4];

    auto issueX = [&](short8 (&xf)[2][4], int c) {
        long base = (long)c * BM + w * 32;
        #pragma unroll
        for (int t = 0; t < 2; ++t) {
            long m = base + t * 16 + p;
            if (m > (long)M - 1) m = (long)M - 1;
            const short* src = X + m * 128 + q * 8;
            #pragma unroll
            for (int kk = 0; kk < 4; ++kk)
                xf[t][kk] = gload16(src + kk * 32);
        }
        SB0();
    };

    auto computeStore = [&](const short8 (&xf)[2][4], int c) {
        long base = (long)c * BM + w * 32;
        f32x4 acc[8][2];
        #pragma unroll
        for (int cc = 0; cc < 8; ++cc)
            #pragma unroll
            for (int t = 0; t < 2; ++t)
                acc[cc][t] = (f32x4){0.f, 0.f, 0.f, 0.f};

        #pragma unroll
        for (int kk = 0; kk < 4; ++kk) {
            short8 af[8];
            #pragma unroll
            for (int cc = 0; cc < 8; ++cc)
                af[cc] = *(const short8*)(sW1 + (cc * 16 + p) * 136 + kk * 32 + q * 8);
            #pragma unroll
            for (int cc = 0; cc < 8; ++cc)
                #pragma unroll
                for (int t = 0; t < 2; ++t)
                    acc[cc][t] = __builtin_amdgcn_mfma_f32_16x16x32_bf16(af[cc], xf[t][kk], acc[cc][t], 0, 0, 0);
        }

        #pragma unroll
        for (int cc = 0; cc < 8; ++cc) {
            f32x4 bb = *(const f32x4*)(b1g + cc * 16 + q * 4);
            #pragma unroll
            for (int t = 0; t < 2; ++t) {
                u32x2 u;
                u[0] = cvtpk(fmaxf(acc[cc][t][0] + bb[0], 0.f), fmaxf(acc[cc][t][1] + bb[1], 0.f));
                u[1] = cvtpk(fmaxf(acc[cc][t][2] + bb[2], 0.f), fmaxf(acc[cc][t][3] + bb[3], 0.f));
                *(u32x2*)(sH + (w * 32 + t * 16 + p) * 136 + cc * 16 + q * 4) = u;
            }
        }
        asm volatile("s_waitcnt lgkmcnt(0)" ::: "memory");

        f32x4 acc2[8][2];
        #pragma unroll
        for (int cc = 0; cc < 8; ++cc)
            #pragma unroll
            for (int t = 0; t < 2; ++t)
                acc2[cc][t] = (f32x4){0.f, 0.f, 0.f, 0.f};

        #pragma unroll
        for (int kk = 0; kk < 4; ++kk) {
            short8 af[8], bfr[2];
            #pragma unroll
            for (int cc = 0; cc < 8; ++cc)
                af[cc] = *(const short8*)(sW2 + (cc * 16 + p) * 136 + kk * 32 + q * 8);
            #pragma unroll
            for (int t = 0; t < 2; ++t)
                bfr[t] = *(const short8*)(sH + (w * 32 + t * 16 + p) * 136 + kk * 32 + q * 8);
            #pragma unroll
            for (int cc = 0; cc < 8; ++cc)
                #pragma unroll
                for (int t = 0; t < 2; ++t)
                    acc2[cc][t] = __builtin_amdgcn_mfma_f32_16x16x32_bf16(af[cc], bfr[t], acc2[cc][t], 0, 0, 0);
        }

        #pragma unroll
        for (int cc = 0; cc < 8; ++cc) {
            f32x4 bb = *(const f32x4*)(b2g + cc * 16 + q * 4);
            #pragma unroll
            for (int t = 0; t < 2; ++t) {
                long m = base + t * 16 + p;
                if (m < M) {
                    u32x2 u;
                    u[0] = cvtpk(fmaxf(acc2[cc][t][0] + bb[0], 0.f), fmaxf(acc2[cc][t][1] + bb[1], 0.f));
                    u[1] = cvtpk(fmaxf(acc2[cc][t][2] + bb[2], 0.f), fmaxf(acc2[cc][t][3] + bb[3], 0.f));
                    *(u32x2*)(z + m * 128 + cc * 16 + q * 4) = u;
                }
            }
        }
    };

    int c = c0;
    issueX(xfA, c);
    asm volatile("s_waitcnt vmcnt(0)" ::: "memory");
    SB0();
    while (true) {
        {
            bool hn = (c + cstr < nChunks);
            if (hn) issueX(xfB, c + cstr);
            computeStore(xfA, c);
            c += cstr;
            if (!hn) return;
            asm volatile("s_waitcnt vmcnt(16)" ::: "memory");
            SB0();
        }
        {
            bool hn = (c + cstr < nChunks);
            if (hn) issueX(xfA, c + cstr);
            computeStore(xfB, c);
            c += cstr;
            if (!hn) return;
            asm volatile("s_waitcnt vmcnt(16)" ::: "memory");
            SB0();
        }
    }
}

// ---------------- merged update MLP: X = concat(h bf16, m bf16), K1=256 ----------------
// NW=7 (448 thr): LDS 159,488B via tight pads -> 7 waves/CU.
template<int NW>
__global__ __launch_bounds__(NW * 64, 1)
void mlp2_upd_all(const short* __restrict__ hvb, const short* __restrict__ hcb,
                  const short* __restrict__ mv, const short* __restrict__ mc,
                  const short* __restrict__ wt_u1, const float* __restrict__ ub1,
                  const short* __restrict__ wt_u2, const float* __restrict__ ub2,
                  float* __restrict__ out, int splitV)
{
    constexpr int BM = NW * 32;
    constexpr int NT = NW * 64;
    __shared__ short sW1[128 * 260];   // K=256, pad 4
    __shared__ short sW2[128 * 132];   // pad 4
    __shared__ short sH[BM * 132];     // pad 4

    const int tid = threadIdx.x;
    const int lane = tid & 63;
    const int w = tid >> 6;
    const int p = lane & 15;
    const int q = lane >> 4;

    int b = blockIdx.x;
    const short *X, *X2; float* O; int M, c0, cstr, set;
    if (b < splitV) {
        set = 0; X = hvb; X2 = mv; O = out; M = NVV; c0 = b; cstr = splitV;
    } else {
        set = 1; X = hcb; X2 = mc; O = out + (size_t)NVV * 128; M = NCC;
        c0 = b - splitV; cstr = gridDim.x - splitV;
    }
    const int nChunks = (M + BM - 1) / BM;

    const short* W1T = wt_u1 + set * 32768;
    const short* W2T = wt_u2 + set * 16384;
    const float* B1 = ub1 + set * 128;
    const float* B2 = ub2 + set * 128;

    for (int e = tid * 8; e < 128 * 256; e += NT * 8) {
        int n = e >> 8, k = e & 255;
        *(short8*)(sW1 + n * 260 + k) = *(const short8*)(W1T + e);
    }
    for (int e = tid * 8; e < 128 * 128; e += NT * 8) {
        int n = e >> 7, k = e & 127;
        *(short8*)(sW2 + n * 132 + k) = *(const short8*)(W2T + e);
    }
    __syncthreads();

    if (c0 >= nChunks) return;

    short8 hA[2][4], hB[2][4], mr[2][4];

    auto issueH = [&](short8 (&h)[2][4], int c) {
        long base = (long)c * BM + w * 32;
        #pragma unroll
        for (int t = 0; t < 2; ++t) {
            long m = base + t * 16 + p;
            if (m > (long)M - 1) m = (long)M - 1;
            const short* s1 = X + m * 128 + q * 8;
            #pragma unroll
            for (int kk = 0; kk < 4; ++kk)
                h[t][kk] = gload16(s1 + kk * 32);
        }
        SB0();
    };
    auto issueM = [&](int c) {
        long base = (long)c * BM + w * 32;
        #pragma unroll
        for (int t = 0; t < 2; ++t) {
            long m = base + t * 16 + p;
            if (m > (long)M - 1) m = (long)M - 1;
            const short* s2 = X2 + m * 128 + q * 8;
            #pragma unroll
            for (int kk = 0; kk < 4; ++kk)
                mr[t][kk] = gload16(s2 + kk * 32);
        }
        SB0();
    };

    auto body = [&](const short8 (&h)[2][4], int c, bool hn, int cn) {
        long base = (long)c * BM + w * 32;
        f32x4 acc[8][2];
        #pragma unroll
        for (int cc = 0; cc < 8; ++cc)
            #pragma unroll
            for (int t = 0; t < 2; ++t)
                acc[cc][t] = (f32x4){0.f, 0.f, 0.f, 0.f};

        #pragma unroll
        for (int kk = 0; kk < 8; ++kk) {
            short8 af[8];
            #pragma unroll
            for (int cc = 0; cc < 8; ++cc)
                af[cc] = *(const short8*)(sW1 + (cc * 16 + p) * 260 + kk * 32 + q * 8);
            #pragma unroll
            for (int cc = 0; cc < 8; ++cc)
                #pragma unroll
                for (int t = 0; t < 2; ++t) {
                    short8 xcur = (kk < 4) ? h[t][kk] : mr[t][kk - 4];
                    acc[cc][t] = __builtin_amdgcn_mfma_f32_16x16x32_bf16(af[cc], xcur, acc[cc][t], 0, 0, 0);
                }
        }

        if (hn) issueM(cn);

        #pragma unroll
        for (int cc = 0; cc < 8; ++cc) {
            f32x4 bb = *(const f32x4*)(B1 + cc * 16 + q * 4);
            #pragma unroll
            for (int t = 0; t < 2; ++t) {
                u32x2 u;
                u[0] = cvtpk(fmaxf(acc[cc][t][0] + bb[0], 0.f), fmaxf(acc[cc][t][1] + bb[1], 0.f));
                u[1] = cvtpk(fmaxf(acc[cc][t][2] + bb[2], 0.f), fmaxf(acc[cc][t][3] + bb[3], 0.f));
                *(u32x2*)(sH + (w * 32 + t * 16 + p) * 132 + cc * 16 + q * 4) = u;
            }
        }
        asm volatile("s_waitcnt lgkmcnt(0)" ::: "memory");

        f32x4 acc2[8][2];
        #pragma unroll
        for (int cc = 0; cc < 8; ++cc)
            #pragma unroll
            for (int t = 0; t < 2; ++t)
                acc2[cc][t] = (f32x4){0.f, 0.f, 0.f, 0.f};

        #pragma unroll
        for (int kk = 0; kk < 4; ++kk) {
            short8 af[8], bfr[2];
            #pragma unroll
            for (int cc = 0; cc < 8; ++cc)
                af[cc] = *(const short8*)(sW2 + (cc * 16 + p) * 132 + kk * 32 + q * 8);
            #pragma unroll
            for (int t = 0; t < 2; ++t)
                bfr[t] = *(const short8*)(sH + (w * 32 + t * 16 + p) * 132 + kk * 32 + q * 8);
            #pragma unroll
            for (int cc = 0; cc < 8; ++cc)
                #pragma unroll
                for (int t = 0; t < 2; ++t)
                    acc2[cc][t] = __builtin_amdgcn_mfma_f32_16x16x32_bf16(af[cc], bfr[t], acc2[cc][t], 0, 0, 0);
        }

        #pragma unroll
        for (int cc = 0; cc < 8; ++cc) {
            f32x4 bb = *(const f32x4*)(B2 + cc * 16 + q * 4);
            #pragma unroll
            for (int t = 0; t < 2; ++t) {
                long m = base + t * 16 + p;
                if (m < M) {
                    f32x4 fv;
                    #pragma unroll
                    for (int i = 0; i < 4; ++i)
                        fv[i] = fmaxf(acc2[cc][t][i] + bb[i], 0.f);
                    *(f32x4*)(O + m * 128 + cc * 16 + q * 4) = fv;
                }
            }
        }
    };

    int c = c0;
    issueH(hA, c);
    issueM(c);
    asm volatile("s_waitcnt vmcnt(0)" ::: "memory");
    SB0();
    while (true) {
        {
            bool hn = (c + cstr < nChunks);
            if (hn) issueH(hB, c + cstr);
            body(hA, c, hn, c + cstr);
            c += cstr;
            if (!hn) return;
            asm volatile("s_waitcnt vmcnt(16)" ::: "memory");
            SB0();
        }
        {
            bool hn = (c + cstr < nChunks);
            if (hn) issueH(hA, c + cstr);
            body(hB, c, hn, c + cstr);
            c += cstr;
            if (!hn) return;
            asm volatile("s_waitcnt vmcnt(16)" ::: "memory");
            SB0();
        }
    }
}

// ---------------- CSR build ----------------

__global__ __launch_bounds__(256)
void seg_reduce2(const int* __restrict__ cnt_v, const int* __restrict__ cnt_c,
                 int* __restrict__ bsum_v, int* __restrict__ bsum_c, int Bv)
{
    __shared__ int s[256];
    int b = blockIdx.x, t = threadIdx.x;
    const int* counts; int* bsum; int N; int bb;
    if (b < Bv) { counts = cnt_v; bsum = bsum_v; N = NVV; bb = b; }
    else        { counts = cnt_c; bsum = bsum_c; N = NCC; bb = b - Bv; }
    int base = bb * 512;
    int v = 0;
    if (base + t < N) v += counts[base + t];
    if (base + 256 + t < N) v += counts[base + 256 + t];
    s[t] = v;
    __syncthreads();
    for (int off = 128; off > 0; off >>= 1) {
        if (t < off) s[t] += s[t + off];
        __syncthreads();
    }
    if (t == 0) bsum[bb] = s[0];
}

__global__ __launch_bounds__(1024)
void scan_bsum2(int* __restrict__ bsum_v, int* __restrict__ bsum_c, int Bv, int Bc)
{
    __shared__ int s[1024];
    int* bsum = (blockIdx.x == 0) ? bsum_v : bsum_c;
    int B = (blockIdx.x == 0) ? Bv : Bc;
    int t = threadIdx.x;
    s[t] = (t < B) ? bsum[t] : 0;
    __syncthreads();
    for (int off = 1; off < 1024; off <<= 1) {
        int v = (t >= off) ? s[t - off] : 0;
        __syncthreads();
        s[t] += v;
        __syncthreads();
    }
    if (t < B) bsum[t] = (t == 0) ? 0 : s[t - 1];
}

__global__ __launch_bounds__(512)
void scan_final2(const int* __restrict__ cnt_v, const int* __restrict__ cnt_c,
                 const int* __restrict__ bsum_v, const int* __restrict__ bsum_c,
                 int* __restrict__ offs_v, int* __restrict__ offs_c, int Bv)
{
    __shared__ int s[512];
    int b = blockIdx.x, t = threadIdx.x;
    const int* counts; const int* bsum; int* offs; int N; int bb;
    if (b < Bv) { counts = cnt_v; bsum = bsum_v; offs = offs_v; N = NVV; bb = b; }
    else        { counts = cnt_c; bsum = bsum_c; offs = offs_c; N = NCC; bb = b - Bv; }
    int idx = bb * 512 + t;
    int c = (idx < N) ? counts[idx] : 0;
    s[t] = c;
    __syncthreads();
    for (int off = 1; off < 512; off <<= 1) {
        int v = (t >= off) ? s[t - off] : 0;
        __syncthreads();
        s[t] += v;
        __syncthreads();
    }
    if (idx < N) offs[idx] = bsum[bb] + s[t] - c;
    if (idx == N - 1) offs[N] = bsum[bb] + s[t];
}

// XCD-partitioned CSR fill: each block group's stores land only in its
// 1.6MB edge slice -> L2-resident, dense line fill (kills the 16x write amp).
__global__ __launch_bounds__(256)
void csr_fill_xcd(const int* __restrict__ row_v, const int* __restrict__ col_v,
                  const int* __restrict__ row_c, const int* __restrict__ col_c,
                  const int* __restrict__ offs_v, const int* __restrict__ offs_c,
                  int* __restrict__ cur_v, int* __restrict__ cur_c,
                  int* __restrict__ edge_v, int* __restrict__ edge_c)
{
    const int g = blockIdx.x & 7;
    const int bg = blockIdx.x >> 3, nbg = gridDim.x >> 3;
    const int r0 = g * (NVV / 8), r1 = r0 + NVV / 8;
    for (int e = bg * 256 + threadIdx.x; e < NEE; e += nbg * 256) {
        int r = row_v[e];
        if (r >= r0 && r < r1) {
            int pos = offs_v[r] + atomicAdd(&cur_v[r], 1);
            edge_v[pos] = col_v[e];
        }
    }
    const int s0 = g * (NCC / 8), s1 = s0 + NCC / 8;
    for (int e = bg * 256 + threadIdx.x; e < NEE; e += nbg * 256) {
        int r = row_c[e];
        if (r >= s0 && r < s1) {
            int pos = offs_c[r] + atomicAdd(&cur_c[r], 1);
            edge_c[pos] = col_c[e];
        }
    }
}

// merged gather: rows [0,NVV) from zv -> mv, rows [NVV, NVV+NCC) from zc -> mc
__global__ __launch_bounds__(256)
void csr_gather_all(const short* __restrict__ zv, const short* __restrict__ zc,
                    const int* __restrict__ offs_v, const int* __restrict__ edge_v,
                    const int* __restrict__ offs_c, const int* __restrict__ edge_c,
                    short* __restrict__ mv, short* __restrict__ mc)
{
    int wid = (int)((blockIdx.x * 256 + threadIdx.x) >> 6);
    int lane = threadIdx.x & 63;
    int sub = lane >> 4;
    int sl = lane & 15;
    int row = wid * 4 + sub;
    if (row >= NVV + NCC) return;

    const short* z; const int* offs; const int* ec; short* md; int r;
    if (row < NVV) { z = zv; offs = offs_v; ec = edge_v; md = mv; r = row; }
    else           { z = zc; offs = offs_c; ec = edge_c; md = mc; r = row - NVV; }

    int beg = offs[r], end = offs[r + 1];

    float a[8];
    #pragma unroll
    for (int i = 0; i < 8; ++i) a[i] = 0.f;

    int j = beg;
    for (; j + 3 < end; j += 4) {
        int c0 = ec[j], c1 = ec[j + 1], c2 = ec[j + 2], c3 = ec[j + 3];
        short8 v0 = *(const short8*)(z + (long)c0 * 128 + sl * 8);
        short8 v1 = *(const short8*)(z + (long)c1 * 128 + sl * 8);
        short8 v2 = *(const short8*)(z + (long)c2 * 128 + sl * 8);
        short8 v3 = *(const short8*)(z + (long)c3 * 128 + sl * 8);
        #pragma unroll
        for (int i = 0; i < 8; ++i)
            a[i] += (b2f(v0[i]) + b2f(v1[i])) + (b2f(v2[i]) + b2f(v3[i]));
    }
    for (; j < end; ++j) {
        int c = ec[j];
        short8 v = *(const short8*)(z + (long)c * 128 + sl * 8);
        #pragma unroll
        for (int i = 0; i < 8; ++i) a[i] += b2f(v[i]);
    }

    u32x4 o;
    o[0] = cvtpk(a[0], a[1]);
    o[1] = cvtpk(a[2], a[3]);
    o[2] = cvtpk(a[4], a[5]);
    o[3] = cvtpk(a[6], a[7]);
    *(u32x4*)(md + (long)r * 128 + sl * 8) = o;
}

extern "C" void kernel_launch(void* const* d_in, const int* in_sizes, int n_in,
                              void* d_out, int out_size, void* d_ws, size_t ws_size,
                              hipStream_t stream)
{
    const float* hv   = (const float*)d_in[0];
    const float* hc   = (const float*)d_in[1];
    const int* row_v  = (const int*)d_in[2];
    const int* col_v  = (const int*)d_in[3];
    const int* row_c  = (const int*)d_in[4];
    const int* col_c  = (const int*)d_in[5];
    const float* mw1  = (const float*)d_in[6];
    const float* mb1  = (const float*)d_in[7];
    const float* mw2  = (const float*)d_in[8];
    const float* mb2  = (const float*)d_in[9];
    const float* uw1  = (const float*)d_in[10];
    const float* ub1  = (const float*)d_in[11];
    const float* uw2  = (const float*)d_in[12];
    const float* ub2  = (const float*)d_in[13];
    float* out = (float*)d_out;

    short* zv = (short*)d_ws;
    short* zc = zv + (size_t)2 * NCC * 128;
    short* mv = zc + (size_t)2 * NVV * 128;
    short* mc = mv + (size_t)NVV * 128;
    short* wt_m1 = mc + (size_t)NCC * 128;      // 4 * 16384
    short* wt_m2 = wt_m1 + 4 * 16384;
    short* wt_u1 = wt_m2 + 4 * 16384;           // 2 * 32768
    short* wt_u2 = wt_u1 + 2 * 32768;           // 2 * 16384
    short* hvb = wt_u2 + 2 * 16384;
    short* hcb = hvb + (size_t)NVV * 128;
    int* edge_v = (int*)(hcb + (size_t)NCC * 128);
    int* edge_c = edge_v + NEE;
    int* offs_v = edge_c + NEE;
    int* offs_c = offs_v + (NVV + 1);
    int* cnt_v  = offs_c + (NCC + 1);
    int* cnt_c  = cnt_v + NVV;        // cnt_v,cnt_c,cur_v,cur_c contiguous -> one memset
    int* cur_v  = cnt_c + NCC;
    int* cur_c  = cur_v + NVV;
    int* bsum_v = cur_c + NCC;
    int* bsum_c = bsum_v + 1024;

    const int Bv = (NVV + 511) / 512;   // 196
    const int Bc = (NCC + 511) / 512;   // 782

    // ---- single memset for hist counters + fill cursors
    hipMemsetAsync(cnt_v, 0, 2 * (NVV + NCC) * sizeof(int), stream);

    // ---- phase1: XCD hist (2048 blocks) + to_bf16 + weight prep in one launch
    phase1<<<4992, 256, 0, stream>>>(
        row_v, row_c, cnt_v, cnt_c,
        hv, hc, hvb, hcb,
        mw1, mw2, uw1, uw2, wt_m1, wt_m2, wt_u1, wt_u2);

    // ---- scans
    seg_reduce2<<<Bv + Bc, 256, 0, stream>>>(cnt_v, cnt_c, bsum_v, bsum_c, Bv);
    scan_bsum2<<<2, 1024, 0, stream>>>(bsum_v, bsum_c, Bv, Bc);
    scan_final2<<<Bv + Bc, 512, 0, stream>>>(cnt_v, cnt_c, bsum_v, bsum_c, offs_v, offs_c, Bv);

    // ---- CSR fill (XCD-partitioned)
    csr_fill_xcd<<<1024, 256, 0, stream>>>(
        row_v, col_v, row_c, col_c, offs_v, offs_c, cur_v, cur_c, edge_v, edge_c);

    // ---- message MLPs, one launch: blocks [0,204) hc sets 0/1, [204,256) hv sets 2/3
    mlp2_msg_all<8><<<256, 512, 0, stream>>>(
        hcb, hvb, wt_m1, mb1, wt_m2, mb2, zv, zc, 204);

    // ---- segment sums, one launch (both graphs)
    csr_gather_all<<<((NVV + NCC) / 4 + 3) / 4, 256, 0, stream>>>(
        zv, zc, offs_v, edge_v, offs_c, edge_c, mv, mc);

    // ---- update MLPs, one launch (NW=7): blocks [0,51) v-side, rest c-side
    mlp2_upd_all<7><<<256, 448, 0, stream>>>(
        hvb, hcb, mv, mc, wt_u1, ub1, wt_u2, ub2, out, 51);
}

// Round 13
// 1060.729 us; speedup vs baseline: 1.0648x; 1.0648x over previous
//
#include <hip/hip_runtime.h>
#include <hip/hip_bf16.h>

#define NVV 100000
#define NCC 400000
#define NEE 1600000

typedef short short8 __attribute__((ext_vector_type(8)));
typedef short short4v __attribute__((ext_vector_type(4)));
typedef float f32x4 __attribute__((ext_vector_type(4)));
typedef unsigned int u32x2 __attribute__((ext_vector_type(2)));
typedef unsigned int u32x4 __attribute__((ext_vector_type(4)));

__device__ __forceinline__ float b2f(short s) {
    unsigned int u = ((unsigned int)(unsigned short)s) << 16;
    return __builtin_bit_cast(float, u);
}
__device__ __forceinline__ short f2b(float f) {
    __hip_bfloat16 h = __float2bfloat16(f);
    return __builtin_bit_cast(short, h);
}
// packed f32->bf16 (RTNE), 2 elements per instruction
__device__ __forceinline__ unsigned int cvtpk(float a, float b) {
    unsigned int r;
    asm("v_cvt_pk_bf16_f32 %0, %1, %2" : "=v"(r) : "v"(a), "v"(b));
    return r;
}
// async 16B global load: compiler cannot sink it; result valid after counted vmcnt
__device__ __forceinline__ short8 gload16(const short* p) {
    short8 d;
    asm volatile("global_load_dwordx4 %0, %1, off" : "=v"(d) : "v"(p));
    return d;
}
#define SB0() __builtin_amdgcn_sched_barrier(0)

// ---------------- phase1: hist (XCD-partitioned, 1024 blocks) + f32->bf16 convert + weight prep ----------------
// blocks [0,1024): hist | [1024,3072): to_bf16 | [3072,3968): prep.
// ROUND-10 PROVEN OPTIMUM: 1024 hist blocks (128/group). Round 11 (512, single-pass)
// and round 12 (2048) both regressed -- atomic-throughput + interference limited.
__global__ __launch_bounds__(256)
void phase1(const int* __restrict__ row_v, const int* __restrict__ row_c,
            int* __restrict__ cnt_v, int* __restrict__ cnt_c,
            const float* __restrict__ hv, const float* __restrict__ hc,
            short* __restrict__ hvb, short* __restrict__ hcb,
            const float* __restrict__ mw1, const float* __restrict__ mw2,
            const float* __restrict__ uw1, const float* __restrict__ uw2,
            short* __restrict__ wt_m1, short* __restrict__ wt_m2,
            short* __restrict__ wt_u1, short* __restrict__ wt_u2)
{
    int b = blockIdx.x;
    if (b < 1024) {
        // XCD-partitioned histogram: group g owns row slice -> cnt slice stays in one L2
        const int g = b & 7;
        const int bg = b >> 3, nbg = 128;
        const int r0 = g * (NVV / 8), r1 = r0 + NVV / 8;
        for (int e = bg * 256 + threadIdx.x; e < NEE; e += nbg * 256) {
            int r = row_v[e];
            if (r >= r0 && r < r1) atomicAdd(&cnt_v[r], 1);
        }
        const int s0 = g * (NCC / 8), s1 = s0 + NCC / 8;
        for (int e = bg * 256 + threadIdx.x; e < NEE; e += nbg * 256) {
            int r = row_c[e];
            if (r >= s0 && r < s1) atomicAdd(&cnt_c[r], 1);
        }
    } else if (b < 3072) {
        const long nv = (long)NVV * 128;
        const long nc = (long)NCC * 128;
        long i0 = ((long)(b - 1024) * 256 + threadIdx.x) * 8;
        long stride = (long)2048 * 256 * 8;
        for (long i = i0; i < nv + nc; i += stride) {
            const float* in; short* outp; long j;
            if (i < nv) { in = hv; outp = hvb; j = i; }
            else        { in = hc; outp = hcb; j = i - nv; }
            f32x4 a = *(const f32x4*)(in + j);
            f32x4 bq = *(const f32x4*)(in + j + 4);
            u32x4 o;
            o[0] = cvtpk(a[0], a[1]);
            o[1] = cvtpk(a[2], a[3]);
            o[2] = cvtpk(bq[0], bq[1]);
            o[3] = cvtpk(bq[2], bq[3]);
            *(u32x4*)(outp + j) = o;
        }
    } else {
        int e = (b - 3072) * 256 + threadIdx.x;
        const float* W; short* WT; int K; int idx;
        if (e < 65536)        { W = mw1; WT = wt_m1; K = 128; idx = e; }
        else if (e < 131072)  { W = mw2; WT = wt_m2; K = 128; idx = e - 65536; }
        else if (e < 196608)  { W = uw1; WT = wt_u1; K = 256; idx = e - 131072; }
        else if (e < 229376)  { W = uw2; WT = wt_u2; K = 128; idx = e - 196608; }
        else return;
        int mk = idx >> 7, n = idx & 127;
        int mi = mk / K, k = mk - mi * K;
        WT[(size_t)mi * K * 128 + (size_t)n * K + k] = f2b(W[idx]);
    }
}

// ---------------- merged message MLP (hc sets 0,1 -> zv; hv sets 2,3 -> zc) ----------------
template<int NW>
__global__ __launch_bounds__(NW * 64, 1)
void mlp2_msg_all(const short* __restrict__ hcb, const short* __restrict__ hvb,
                  const short* __restrict__ WT1, const float* __restrict__ B1a,
                  const short* __restrict__ WT2, const float* __restrict__ B2a,
                  short* __restrict__ zv, short* __restrict__ zc, int splitC)
{
    constexpr int BM = NW * 32;
    constexpr int NT = NW * 64;
    __shared__ short sW1[128 * 136];
    __shared__ short sW2[128 * 136];
    __shared__ short sH[BM * 136];

    const int tid = threadIdx.x;
    const int lane = tid & 63;
    const int w = tid >> 6;
    const int p = lane & 15;
    const int q = lane >> 4;

    int b = blockIdx.x;
    const short* X; short* z; int M, c0, cstr, set;
    if (b < splitC) {
        set = b & 1; X = hcb; z = zv + (size_t)set * NCC * 128;
        M = NCC; c0 = b >> 1; cstr = splitC >> 1;
    } else {
        int bb = b - splitC;
        set = 2 + (bb & 1); X = hvb; z = zc + (size_t)(bb & 1) * NVV * 128;
        M = NVV; c0 = bb >> 1; cstr = (gridDim.x - splitC) >> 1;
    }
    const int nChunks = (M + BM - 1) / BM;

    const short* w1g = WT1 + set * 16384;
    const short* w2g = WT2 + set * 16384;
    const float* b1g = B1a + set * 128;
    const float* b2g = B2a + set * 128;

    for (int e = tid * 8; e < 128 * 128; e += NT * 8) {
        int n = e >> 7, k = e & 127;
        *(short8*)(sW1 + n * 136 + k) = *(const short8*)(w1g + e);
        *(short8*)(sW2 + n * 136 + k) = *(const short8*)(w2g + e);
    }
    __syncthreads();

    if (c0 >= nChunks) return;

    short8 xfA[2][4], xfB[2][4];

    auto issueX = [&](short8 (&xf)[2][4], int c) {
        long base = (long)c * BM + w * 32;
        #pragma unroll
        for (int t = 0; t < 2; ++t) {
            long m = base + t * 16 + p;
            if (m > (long)M - 1) m = (long)M - 1;
            const short* src = X + m * 128 + q * 8;
            #pragma unroll
            for (int kk = 0; kk < 4; ++kk)
                xf[t][kk] = gload16(src + kk * 32);
        }
        SB0();
    };

    auto computeStore = [&](const short8 (&xf)[2][4], int c) {
        long base = (long)c * BM + w * 32;
        f32x4 acc[8][2];
        #pragma unroll
        for (int cc = 0; cc < 8; ++cc)
            #pragma unroll
            for (int t = 0; t < 2; ++t)
                acc[cc][t] = (f32x4){0.f, 0.f, 0.f, 0.f};

        #pragma unroll
        for (int kk = 0; kk < 4; ++kk) {
            short8 af[8];
            #pragma unroll
            for (int cc = 0; cc < 8; ++cc)
                af[cc] = *(const short8*)(sW1 + (cc * 16 + p) * 136 + kk * 32 + q * 8);
            #pragma unroll
            for (int cc = 0; cc < 8; ++cc)
                #pragma unroll
                for (int t = 0; t < 2; ++t)
                    acc[cc][t] = __builtin_amdgcn_mfma_f32_16x16x32_bf16(af[cc], xf[t][kk], acc[cc][t], 0, 0, 0);
        }

        #pragma unroll
        for (int cc = 0; cc < 8; ++cc) {
            f32x4 bb = *(const f32x4*)(b1g + cc * 16 + q * 4);
            #pragma unroll
            for (int t = 0; t < 2; ++t) {
                u32x2 u;
                u[0] = cvtpk(fmaxf(acc[cc][t][0] + bb[0], 0.f), fmaxf(acc[cc][t][1] + bb[1], 0.f));
                u[1] = cvtpk(fmaxf(acc[cc][t][2] + bb[2], 0.f), fmaxf(acc[cc][t][3] + bb[3], 0.f));
                *(u32x2*)(sH + (w * 32 + t * 16 + p) * 136 + cc * 16 + q * 4) = u;
            }
        }
        asm volatile("s_waitcnt lgkmcnt(0)" ::: "memory");

        f32x4 acc2[8][2];
        #pragma unroll
        for (int cc = 0; cc < 8; ++cc)
            #pragma unroll
            for (int t = 0; t < 2; ++t)
                acc2[cc][t] = (f32x4){0.f, 0.f, 0.f, 0.f};

        #pragma unroll
        for (int kk = 0; kk < 4; ++kk) {
            short8 af[8], bfr[2];
            #pragma unroll
            for (int cc = 0; cc < 8; ++cc)
                af[cc] = *(const short8*)(sW2 + (cc * 16 + p) * 136 + kk * 32 + q * 8);
            #pragma unroll
            for (int t = 0; t < 2; ++t)
                bfr[t] = *(const short8*)(sH + (w * 32 + t * 16 + p) * 136 + kk * 32 + q * 8);
            #pragma unroll
            for (int cc = 0; cc < 8; ++cc)
                #pragma unroll
                for (int t = 0; t < 2; ++t)
                    acc2[cc][t] = __builtin_amdgcn_mfma_f32_16x16x32_bf16(af[cc], bfr[t], acc2[cc][t], 0, 0, 0);
        }

        #pragma unroll
        for (int cc = 0; cc < 8; ++cc) {
            f32x4 bb = *(const f32x4*)(b2g + cc * 16 + q * 4);
            #pragma unroll
            for (int t = 0; t < 2; ++t) {
                long m = base + t * 16 + p;
                if (m < M) {
                    u32x2 u;
                    u[0] = cvtpk(fmaxf(acc2[cc][t][0] + bb[0], 0.f), fmaxf(acc2[cc][t][1] + bb[1], 0.f));
                    u[1] = cvtpk(fmaxf(acc2[cc][t][2] + bb[2], 0.f), fmaxf(acc2[cc][t][3] + bb[3], 0.f));
                    *(u32x2*)(z + m * 128 + cc * 16 + q * 4) = u;
                }
            }
        }
    };

    int c = c0;
    issueX(xfA, c);
    asm volatile("s_waitcnt vmcnt(0)" ::: "memory");
    SB0();
    while (true) {
        {
            bool hn = (c + cstr < nChunks);
            if (hn) issueX(xfB, c + cstr);
            computeStore(xfA, c);
            c += cstr;
            if (!hn) return;
            asm volatile("s_waitcnt vmcnt(16)" ::: "memory");
            SB0();
        }
        {
            bool hn = (c + cstr < nChunks);
            if (hn) issueX(xfA, c + cstr);
            computeStore(xfB, c);
            c += cstr;
            if (!hn) return;
            asm volatile("s_waitcnt vmcnt(16)" ::: "memory");
            SB0();
        }
    }
}

// ---------------- merged update MLP: X = concat(h bf16, m bf16), K1=256 ----------------
// NW=7 (448 thr): LDS 159,488B via tight pads -> 7 waves/CU.
template<int NW>
__global__ __launch_bounds__(NW * 64, 1)
void mlp2_upd_all(const short* __restrict__ hvb, const short* __restrict__ hcb,
                  const short* __restrict__ mv, const short* __restrict__ mc,
                  const short* __restrict__ wt_u1, const float* __restrict__ ub1,
                  const short* __restrict__ wt_u2, const float* __restrict__ ub2,
                  float* __restrict__ out, int splitV)
{
    constexpr int BM = NW * 32;
    constexpr int NT = NW * 64;
    __shared__ short sW1[128 * 260];   // K=256, pad 4
    __shared__ short sW2[128 * 132];   // pad 4
    __shared__ short sH[BM * 132];     // pad 4

    const int tid = threadIdx.x;
    const int lane = tid & 63;
    const int w = tid >> 6;
    const int p = lane & 15;
    const int q = lane >> 4;

    int b = blockIdx.x;
    const short *X, *X2; float* O; int M, c0, cstr, set;
    if (b < splitV) {
        set = 0; X = hvb; X2 = mv; O = out; M = NVV; c0 = b; cstr = splitV;
    } else {
        set = 1; X = hcb; X2 = mc; O = out + (size_t)NVV * 128; M = NCC;
        c0 = b - splitV; cstr = gridDim.x - splitV;
    }
    const int nChunks = (M + BM - 1) / BM;

    const short* W1T = wt_u1 + set * 32768;
    const short* W2T = wt_u2 + set * 16384;
    const float* B1 = ub1 + set * 128;
    const float* B2 = ub2 + set * 128;

    for (int e = tid * 8; e < 128 * 256; e += NT * 8) {
        int n = e >> 8, k = e & 255;
        *(short8*)(sW1 + n * 260 + k) = *(const short8*)(W1T + e);
    }
    for (int e = tid * 8; e < 128 * 128; e += NT * 8) {
        int n = e >> 7, k = e & 127;
        *(short8*)(sW2 + n * 132 + k) = *(const short8*)(W2T + e);
    }
    __syncthreads();

    if (c0 >= nChunks) return;

    short8 hA[2][4], hB[2][4], mr[2][4];

    auto issueH = [&](short8 (&h)[2][4], int c) {
        long base = (long)c * BM + w * 32;
        #pragma unroll
        for (int t = 0; t < 2; ++t) {
            long m = base + t * 16 + p;
            if (m > (long)M - 1) m = (long)M - 1;
            const short* s1 = X + m * 128 + q * 8;
            #pragma unroll
            for (int kk = 0; kk < 4; ++kk)
                h[t][kk] = gload16(s1 + kk * 32);
        }
        SB0();
    };
    auto issueM = [&](int c) {
        long base = (long)c * BM + w * 32;
        #pragma unroll
        for (int t = 0; t < 2; ++t) {
            long m = base + t * 16 + p;
            if (m > (long)M - 1) m = (long)M - 1;
            const short* s2 = X2 + m * 128 + q * 8;
            #pragma unroll
            for (int kk = 0; kk < 4; ++kk)
                mr[t][kk] = gload16(s2 + kk * 32);
        }
        SB0();
    };

    auto body = [&](const short8 (&h)[2][4], int c, bool hn, int cn) {
        long base = (long)c * BM + w * 32;
        f32x4 acc[8][2];
        #pragma unroll
        for (int cc = 0; cc < 8; ++cc)
            #pragma unroll
            for (int t = 0; t < 2; ++t)
                acc[cc][t] = (f32x4){0.f, 0.f, 0.f, 0.f};

        #pragma unroll
        for (int kk = 0; kk < 8; ++kk) {
            short8 af[8];
            #pragma unroll
            for (int cc = 0; cc < 8; ++cc)
                af[cc] = *(const short8*)(sW1 + (cc * 16 + p) * 260 + kk * 32 + q * 8);
            #pragma unroll
            for (int cc = 0; cc < 8; ++cc)
                #pragma unroll
                for (int t = 0; t < 2; ++t) {
                    short8 xcur = (kk < 4) ? h[t][kk] : mr[t][kk - 4];
                    acc[cc][t] = __builtin_amdgcn_mfma_f32_16x16x32_bf16(af[cc], xcur, acc[cc][t], 0, 0, 0);
                }
        }

        if (hn) issueM(cn);

        #pragma unroll
        for (int cc = 0; cc < 8; ++cc) {
            f32x4 bb = *(const f32x4*)(B1 + cc * 16 + q * 4);
            #pragma unroll
            for (int t = 0; t < 2; ++t) {
                u32x2 u;
                u[0] = cvtpk(fmaxf(acc[cc][t][0] + bb[0], 0.f), fmaxf(acc[cc][t][1] + bb[1], 0.f));
                u[1] = cvtpk(fmaxf(acc[cc][t][2] + bb[2], 0.f), fmaxf(acc[cc][t][3] + bb[3], 0.f));
                *(u32x2*)(sH + (w * 32 + t * 16 + p) * 132 + cc * 16 + q * 4) = u;
            }
        }
        asm volatile("s_waitcnt lgkmcnt(0)" ::: "memory");

        f32x4 acc2[8][2];
        #pragma unroll
        for (int cc = 0; cc < 8; ++cc)
            #pragma unroll
            for (int t = 0; t < 2; ++t)
                acc2[cc][t] = (f32x4){0.f, 0.f, 0.f, 0.f};

        #pragma unroll
        for (int kk = 0; kk < 4; ++kk) {
            short8 af[8], bfr[2];
            #pragma unroll
            for (int cc = 0; cc < 8; ++cc)
                af[cc] = *(const short8*)(sW2 + (cc * 16 + p) * 132 + kk * 32 + q * 8);
            #pragma unroll
            for (int t = 0; t < 2; ++t)
                bfr[t] = *(const short8*)(sH + (w * 32 + t * 16 + p) * 132 + kk * 32 + q * 8);
            #pragma unroll
            for (int cc = 0; cc < 8; ++cc)
                #pragma unroll
                for (int t = 0; t < 2; ++t)
                    acc2[cc][t] = __builtin_amdgcn_mfma_f32_16x16x32_bf16(af[cc], bfr[t], acc2[cc][t], 0, 0, 0);
        }

        #pragma unroll
        for (int cc = 0; cc < 8; ++cc) {
            f32x4 bb = *(const f32x4*)(B2 + cc * 16 + q * 4);
            #pragma unroll
            for (int t = 0; t < 2; ++t) {
                long m = base + t * 16 + p;
                if (m < M) {
                    f32x4 fv;
                    #pragma unroll
                    for (int i = 0; i < 4; ++i)
                        fv[i] = fmaxf(acc2[cc][t][i] + bb[i], 0.f);
                    *(f32x4*)(O + m * 128 + cc * 16 + q * 4) = fv;
                }
            }
        }
    };

    int c = c0;
    issueH(hA, c);
    issueM(c);
    asm volatile("s_waitcnt vmcnt(0)" ::: "memory");
    SB0();
    while (true) {
        {
            bool hn = (c + cstr < nChunks);
            if (hn) issueH(hB, c + cstr);
            body(hA, c, hn, c + cstr);
            c += cstr;
            if (!hn) return;
            asm volatile("s_waitcnt vmcnt(16)" ::: "memory");
            SB0();
        }
        {
            bool hn = (c + cstr < nChunks);
            if (hn) issueH(hA, c + cstr);
            body(hB, c, hn, c + cstr);
            c += cstr;
            if (!hn) return;
            asm volatile("s_waitcnt vmcnt(16)" ::: "memory");
            SB0();
        }
    }
}

// ---------------- CSR build ----------------

__global__ __launch_bounds__(256)
void seg_reduce2(const int* __restrict__ cnt_v, const int* __restrict__ cnt_c,
                 int* __restrict__ bsum_v, int* __restrict__ bsum_c, int Bv)
{
    __shared__ int s[256];
    int b = blockIdx.x, t = threadIdx.x;
    const int* counts; int* bsum; int N; int bb;
    if (b < Bv) { counts = cnt_v; bsum = bsum_v; N = NVV; bb = b; }
    else        { counts = cnt_c; bsum = bsum_c; N = NCC; bb = b - Bv; }
    int base = bb * 512;
    int v = 0;
    if (base + t < N) v += counts[base + t];
    if (base + 256 + t < N) v += counts[base + 256 + t];
    s[t] = v;
    __syncthreads();
    for (int off = 128; off > 0; off >>= 1) {
        if (t < off) s[t] += s[t + off];
        __syncthreads();
    }
    if (t == 0) bsum[bb] = s[0];
}

__global__ __launch_bounds__(1024)
void scan_bsum2(int* __restrict__ bsum_v, int* __restrict__ bsum_c, int Bv, int Bc)
{
    __shared__ int s[1024];
    int* bsum = (blockIdx.x == 0) ? bsum_v : bsum_c;
    int B = (blockIdx.x == 0) ? Bv : Bc;
    int t = threadIdx.x;
    s[t] = (t < B) ? bsum[t] : 0;
    __syncthreads();
    for (int off = 1; off < 1024; off <<= 1) {
        int v = (t >= off) ? s[t - off] : 0;
        __syncthreads();
        s[t] += v;
        __syncthreads();
    }
    if (t < B) bsum[t] = (t == 0) ? 0 : s[t - 1];
}

__global__ __launch_bounds__(512)
void scan_final2(const int* __restrict__ cnt_v, const int* __restrict__ cnt_c,
                 const int* __restrict__ bsum_v, const int* __restrict__ bsum_c,
                 int* __restrict__ offs_v, int* __restrict__ offs_c, int Bv)
{
    __shared__ int s[512];
    int b = blockIdx.x, t = threadIdx.x;
    const int* counts; const int* bsum; int* offs; int N; int bb;
    if (b < Bv) { counts = cnt_v; bsum = bsum_v; offs = offs_v; N = NVV; bb = b; }
    else        { counts = cnt_c; bsum = bsum_c; offs = offs_c; N = NCC; bb = b - Bv; }
    int idx = bb * 512 + t;
    int c = (idx < N) ? counts[idx] : 0;
    s[t] = c;
    __syncthreads();
    for (int off = 1; off < 512; off <<= 1) {
        int v = (t >= off) ? s[t - off] : 0;
        __syncthreads();
        s[t] += v;
        __syncthreads();
    }
    if (idx < N) offs[idx] = bsum[bb] + s[t] - c;
    if (idx == N - 1) offs[N] = bsum[bb] + s[t];
}

// XCD-partitioned CSR fill: each block group's stores land only in its
// 1.6MB edge slice -> L2-resident, dense line fill (kills the 16x write amp).
__global__ __launch_bounds__(256)
void csr_fill_xcd(const int* __restrict__ row_v, const int* __restrict__ col_v,
                  const int* __restrict__ row_c, const int* __restrict__ col_c,
                  const int* __restrict__ offs_v, const int* __restrict__ offs_c,
                  int* __restrict__ cur_v, int* __restrict__ cur_c,
                  int* __restrict__ edge_v, int* __restrict__ edge_c)
{
    const int g = blockIdx.x & 7;
    const int bg = blockIdx.x >> 3, nbg = gridDim.x >> 3;
    const int r0 = g * (NVV / 8), r1 = r0 + NVV / 8;
    for (int e = bg * 256 + threadIdx.x; e < NEE; e += nbg * 256) {
        int r = row_v[e];
        if (r >= r0 && r < r1) {
            int pos = offs_v[r] + atomicAdd(&cur_v[r], 1);
            edge_v[pos] = col_v[e];
        }
    }
    const int s0 = g * (NCC / 8), s1 = s0 + NCC / 8;
    for (int e = bg * 256 + threadIdx.x; e < NEE; e += nbg * 256) {
        int r = row_c[e];
        if (r >= s0 && r < s1) {
            int pos = offs_c[r] + atomicAdd(&cur_c[r], 1);
            edge_c[pos] = col_c[e];
        }
    }
}

// merged gather: rows [0,NVV) from zv -> mv, rows [NVV, NVV+NCC) from zc -> mc
__global__ __launch_bounds__(256)
void csr_gather_all(const short* __restrict__ zv, const short* __restrict__ zc,
                    const int* __restrict__ offs_v, const int* __restrict__ edge_v,
                    const int* __restrict__ offs_c, const int* __restrict__ edge_c,
                    short* __restrict__ mv, short* __restrict__ mc)
{
    int wid = (int)((blockIdx.x * 256 + threadIdx.x) >> 6);
    int lane = threadIdx.x & 63;
    int sub = lane >> 4;
    int sl = lane & 15;
    int row = wid * 4 + sub;
    if (row >= NVV + NCC) return;

    const short* z; const int* offs; const int* ec; short* md; int r;
    if (row < NVV) { z = zv; offs = offs_v; ec = edge_v; md = mv; r = row; }
    else           { z = zc; offs = offs_c; ec = edge_c; md = mc; r = row - NVV; }

    int beg = offs[r], end = offs[r + 1];

    float a[8];
    #pragma unroll
    for (int i = 0; i < 8; ++i) a[i] = 0.f;

    int j = beg;
    for (; j + 3 < end; j += 4) {
        int c0 = ec[j], c1 = ec[j + 1], c2 = ec[j + 2], c3 = ec[j + 3];
        short8 v0 = *(const short8*)(z + (long)c0 * 128 + sl * 8);
        short8 v1 = *(const short8*)(z + (long)c1 * 128 + sl * 8);
        short8 v2 = *(const short8*)(z + (long)c2 * 128 + sl * 8);
        short8 v3 = *(const short8*)(z + (long)c3 * 128 + sl * 8);
        #pragma unroll
        for (int i = 0; i < 8; ++i)
            a[i] += (b2f(v0[i]) + b2f(v1[i])) + (b2f(v2[i]) + b2f(v3[i]));
    }
    for (; j < end; ++j) {
        int c = ec[j];
        short8 v = *(const short8*)(z + (long)c * 128 + sl * 8);
        #pragma unroll
        for (int i = 0; i < 8; ++i) a[i] += b2f(v[i]);
    }

    u32x4 o;
    o[0] = cvtpk(a[0], a[1]);
    o[1] = cvtpk(a[2], a[3]);
    o[2] = cvtpk(a[4], a[5]);
    o[3] = cvtpk(a[6], a[7]);
    *(u32x4*)(md + (long)r * 128 + sl * 8) = o;
}

extern "C" void kernel_launch(void* const* d_in, const int* in_sizes, int n_in,
                              void* d_out, int out_size, void* d_ws, size_t ws_size,
                              hipStream_t stream)
{
    const float* hv   = (const float*)d_in[0];
    const float* hc   = (const float*)d_in[1];
    const int* row_v  = (const int*)d_in[2];
    const int* col_v  = (const int*)d_in[3];
    const int* row_c  = (const int*)d_in[4];
    const int* col_c  = (const int*)d_in[5];
    const float* mw1  = (const float*)d_in[6];
    const float* mb1  = (const float*)d_in[7];
    const float* mw2  = (const float*)d_in[8];
    const float* mb2  = (const float*)d_in[9];
    const float* uw1  = (const float*)d_in[10];
    const float* ub1  = (const float*)d_in[11];
    const float* uw2  = (const float*)d_in[12];
    const float* ub2  = (const float*)d_in[13];
    float* out = (float*)d_out;

    short* zv = (short*)d_ws;
    short* zc = zv + (size_t)2 * NCC * 128;
    short* mv = zc + (size_t)2 * NVV * 128;
    short* mc = mv + (size_t)NVV * 128;
    short* wt_m1 = mc + (size_t)NCC * 128;      // 4 * 16384
    short* wt_m2 = wt_m1 + 4 * 16384;
    short* wt_u1 = wt_m2 + 4 * 16384;           // 2 * 32768
    short* wt_u2 = wt_u1 + 2 * 32768;           // 2 * 16384
    short* hvb = wt_u2 + 2 * 16384;
    short* hcb = hvb + (size_t)NVV * 128;
    int* edge_v = (int*)(hcb + (size_t)NCC * 128);
    int* edge_c = edge_v + NEE;
    int* offs_v = edge_c + NEE;
    int* offs_c = offs_v + (NVV + 1);
    int* cnt_v  = offs_c + (NCC + 1);
    int* cnt_c  = cnt_v + NVV;        // cnt_v,cnt_c,cur_v,cur_c contiguous -> one memset
    int* cur_v  = cnt_c + NCC;
    int* cur_c  = cur_v + NVV;
    int* bsum_v = cur_c + NCC;
    int* bsum_c = bsum_v + 1024;

    const int Bv = (NVV + 511) / 512;   // 196
    const int Bc = (NCC + 511) / 512;   // 782

    // ---- single memset for hist counters + fill cursors
    hipMemsetAsync(cnt_v, 0, 2 * (NVV + NCC) * sizeof(int), stream);

    // ---- phase1: XCD hist (1024 blocks, round-10 optimum) + to_bf16 + weight prep
    phase1<<<3968, 256, 0, stream>>>(
        row_v, row_c, cnt_v, cnt_c,
        hv, hc, hvb, hcb,
        mw1, mw2, uw1, uw2, wt_m1, wt_m2, wt_u1, wt_u2);

    // ---- scans
    seg_reduce2<<<Bv + Bc, 256, 0, stream>>>(cnt_v, cnt_c, bsum_v, bsum_c, Bv);
    scan_bsum2<<<2, 1024, 0, stream>>>(bsum_v, bsum_c, Bv, Bc);
    scan_final2<<<Bv + Bc, 512, 0, stream>>>(cnt_v, cnt_c, bsum_v, bsum_c, offs_v, offs_c, Bv);

    // ---- CSR fill (XCD-partitioned)
    csr_fill_xcd<<<1024, 256, 0, stream>>>(
        row_v, col_v, row_c, col_c, offs_v, offs_c, cur_v, cur_c, edge_v, edge_c);

    // ---- message MLPs, one launch: blocks [0,204) hc sets 0/1, [204,256) hv sets 2/3
    mlp2_msg_all<8><<<256, 512, 0, stream>>>(
        hcb, hvb, wt_m1, mb1, wt_m2, mb2, zv, zc, 204);

    // ---- segment sums, one launch (both graphs)
    csr_gather_all<<<((NVV + NCC) / 4 + 3) / 4, 256, 0, stream>>>(
        zv, zc, offs_v, edge_v, offs_c, edge_c, mv, mc);

    // ---- update MLPs, one launch (NW=7): blocks [0,51) v-side, rest c-side
    mlp2_upd_all<7><<<256, 448, 0, stream>>>(
        hvb, hcb, mv, mc, wt_u1, ub1, wt_u2, ub2, out, 51);
}